// Round 1
// baseline (2938.913 us; speedup 1.0000x reference)
//
#include <hip/hip_runtime.h>
#include <cstdint>
#include <cstddef>

// Problem constants (match reference setup_inputs)
#define N_NODES   100000
#define N_EDGES   1600000
#define D_IN      128
#define HIDDEN    64
#define N_GRAPHS  512
#define N_CLASSES 10

// ---------------------------------------------------------------------------
// Kernel 1: in-degree count (dst only), float accumulate via HW fp32 atomic
// ---------------------------------------------------------------------------
__global__ void deg_count_kernel(const int* __restrict__ dst, float* __restrict__ deg,
                                 int n_edges) {
    int t = blockIdx.x * blockDim.x + threadIdx.x;
    if (t >= n_edges) return;
    unsafeAtomicAdd(&deg[dst[t]], 1.0f);
}

// deg -> dinv = rsqrt(deg + 1)  (self-loop adds 1), in place
__global__ void dinv_kernel(float* __restrict__ deg, int n_nodes) {
    int t = blockIdx.x * blockDim.x + threadIdx.x;
    if (t >= n_nodes) return;
    deg[t] = rsqrtf(deg[t] + 1.0f);
}

// ---------------------------------------------------------------------------
// GEMM: H[n_rows x 64] = X[n_rows x K] @ W[K x 64]
// 64 rows x 64 cols per block, 256 threads, 4x4 register tile per thread.
// ---------------------------------------------------------------------------
template <int K>
__global__ __launch_bounds__(256)
void gemm64_kernel(const float* __restrict__ X, const float* __restrict__ W,
                   float* __restrict__ H, int n_rows) {
    __shared__ float Xs[64][K + 4];   // +4 pad: keeps float4 alignment, breaks bank aliasing
    __shared__ float Ws[K][64];

    const int tid  = threadIdx.x;
    const int row0 = blockIdx.x * 64;

    // stage W (K*64 contiguous floats)
    constexpr int WN4 = K * 64 / 4;
    const float4* W4 = (const float4*)W;
    float4* Ws4 = (float4*)&Ws[0][0];
    for (int i = tid; i < WN4; i += 256) Ws4[i] = W4[i];

    // stage X tile (64 rows x K), guarded
    constexpr int KQ = K / 4;
    for (int i = tid; i < 64 * KQ; i += 256) {
        int r  = i / KQ;
        int k4 = i % KQ;
        int row = row0 + r;
        float4 v = make_float4(0.f, 0.f, 0.f, 0.f);
        if (row < n_rows) v = ((const float4*)(X + (size_t)row * K))[k4];
        *(float4*)&Xs[r][k4 * 4] = v;
    }
    __syncthreads();

    const int cg = (tid & 15) * 4;   // column group (4 cols)
    const int rg = (tid >> 4) * 4;   // row group (4 rows)

    float4 acc0 = make_float4(0.f,0.f,0.f,0.f);
    float4 acc1 = make_float4(0.f,0.f,0.f,0.f);
    float4 acc2 = make_float4(0.f,0.f,0.f,0.f);
    float4 acc3 = make_float4(0.f,0.f,0.f,0.f);

#pragma unroll 8
    for (int k = 0; k < K; k++) {
        float4 w = *(const float4*)&Ws[k][cg];
        float x0 = Xs[rg + 0][k];
        float x1 = Xs[rg + 1][k];
        float x2 = Xs[rg + 2][k];
        float x3 = Xs[rg + 3][k];
        acc0.x += x0 * w.x; acc0.y += x0 * w.y; acc0.z += x0 * w.z; acc0.w += x0 * w.w;
        acc1.x += x1 * w.x; acc1.y += x1 * w.y; acc1.z += x1 * w.z; acc1.w += x1 * w.w;
        acc2.x += x2 * w.x; acc2.y += x2 * w.y; acc2.z += x2 * w.z; acc2.w += x2 * w.w;
        acc3.x += x3 * w.x; acc3.y += x3 * w.y; acc3.z += x3 * w.z; acc3.w += x3 * w.w;
    }

    float4 accs[4] = {acc0, acc1, acc2, acc3};
#pragma unroll
    for (int i = 0; i < 4; i++) {
        int row = row0 + rg + i;
        if (row < n_rows) *(float4*)(H + (size_t)row * 64 + cg) = accs[i];
    }
}

// ---------------------------------------------------------------------------
// Edge aggregation: agg[dst] += h[src] * dinv[src]*dinv[dst]
// 16 threads per edge, each handles 4 consecutive channels (float4 gather,
// 4 scalar HW fp32 atomics scatter).
// ---------------------------------------------------------------------------
__global__ __launch_bounds__(256)
void edge_agg_kernel(const int* __restrict__ src, const int* __restrict__ dst,
                     const float* __restrict__ dinv, const float* __restrict__ h,
                     float* __restrict__ agg, int n_edges) {
    int t = blockIdx.x * blockDim.x + threadIdx.x;
    int e = t >> 4;
    if (e >= n_edges) return;
    int cg = (t & 15) * 4;
    int s = src[e];
    int d = dst[e];
    float coef = dinv[s] * dinv[d];
    float4 v = *(const float4*)(h + (size_t)s * 64 + cg);
    float* out = agg + (size_t)d * 64 + cg;
    unsafeAtomicAdd(out + 0, v.x * coef);
    unsafeAtomicAdd(out + 1, v.y * coef);
    unsafeAtomicAdd(out + 2, v.z * coef);
    unsafeAtomicAdd(out + 3, v.w * coef);
}

// ---------------------------------------------------------------------------
// out = relu(agg + h*dinv^2 + b)   (in place over agg is safe: elementwise)
// 16 threads per node, 4 channels each.
// ---------------------------------------------------------------------------
__global__ __launch_bounds__(256)
void selfloop_bias_relu_kernel(float* __restrict__ agg, const float* __restrict__ h,
                               const float* __restrict__ dinv, const float* __restrict__ b,
                               int n_nodes) {
    int t = blockIdx.x * blockDim.x + threadIdx.x;
    int node = t >> 4;
    if (node >= n_nodes) return;
    int cg = (t & 15) * 4;
    float di = dinv[node];
    float c2 = di * di;
    float4 a  = *(const float4*)(agg + (size_t)node * 64 + cg);
    float4 hv = *(const float4*)(h   + (size_t)node * 64 + cg);
    float4 bv = *(const float4*)(b + cg);
    float4 r;
    r.x = fmaxf(a.x + hv.x * c2 + bv.x, 0.f);
    r.y = fmaxf(a.y + hv.y * c2 + bv.y, 0.f);
    r.z = fmaxf(a.z + hv.z * c2 + bv.z, 0.f);
    r.w = fmaxf(a.w + hv.w * c2 + bv.w, 0.f);
    *(float4*)(agg + (size_t)node * 64 + cg) = r;
}

// ---------------------------------------------------------------------------
// Pooling: batch is SORTED graph ids. One wave per chunk of nodes; lane = channel.
// Register-accumulate runs, flush atomics on graph change -> ~58k atomics total.
// ---------------------------------------------------------------------------
__global__ __launch_bounds__(256)
void pool_kernel(const float* __restrict__ h, const int* __restrict__ batch,
                 float* __restrict__ pooled, float* __restrict__ cnt,
                 int n_nodes, int chunk) {
    int wave = (blockIdx.x * blockDim.x + threadIdx.x) >> 6;
    int lane = threadIdx.x & 63;
    int start = wave * chunk;
    if (start >= n_nodes) return;
    int end = min(start + chunk, n_nodes);

    int cur = batch[start];
    float acc = 0.f;
    float c = 0.f;
    for (int i = start; i < end; i++) {
        int g = batch[i];
        if (g != cur) {
            unsafeAtomicAdd(&pooled[(size_t)cur * 64 + lane], acc);
            if (lane == 0) unsafeAtomicAdd(&cnt[cur], c);
            acc = 0.f; c = 0.f; cur = g;
        }
        acc += h[(size_t)i * 64 + lane];
        c += 1.f;
    }
    unsafeAtomicAdd(&pooled[(size_t)cur * 64 + lane], acc);
    if (lane == 0) unsafeAtomicAdd(&cnt[cur], c);
}

// ---------------------------------------------------------------------------
// Head: pooled mean -> logits (64x10) -> log_softmax. One thread per graph.
// ---------------------------------------------------------------------------
__global__ __launch_bounds__(256)
void head_kernel(const float* __restrict__ pooled, const float* __restrict__ cnt,
                 const float* __restrict__ Wfc, const float* __restrict__ bfc,
                 float* __restrict__ out) {
    __shared__ float Ws[HIDDEN * N_CLASSES];
    __shared__ float bs[N_CLASSES];
    int tid = threadIdx.x;
    for (int i = tid; i < HIDDEN * N_CLASSES; i += 256) Ws[i] = Wfc[i];
    if (tid < N_CLASSES) bs[tid] = bfc[tid];
    __syncthreads();

    int g = blockIdx.x * 256 + tid;
    if (g >= N_GRAPHS) return;

    float inv = 1.f / fmaxf(cnt[g], 1.f);
    float p[HIDDEN];
#pragma unroll
    for (int k = 0; k < HIDDEN; k++) p[k] = pooled[(size_t)g * 64 + k] * inv;

    float lg[N_CLASSES];
    float m = -1e30f;
#pragma unroll
    for (int j = 0; j < N_CLASSES; j++) {
        float a = bs[j];
#pragma unroll
        for (int k = 0; k < HIDDEN; k++) a += p[k] * Ws[k * N_CLASSES + j];
        lg[j] = a;
        m = fmaxf(m, a);
    }
    float s = 0.f;
#pragma unroll
    for (int j = 0; j < N_CLASSES; j++) s += __expf(lg[j] - m);
    float lse = m + __logf(s);
#pragma unroll
    for (int j = 0; j < N_CLASSES; j++) out[(size_t)g * N_CLASSES + j] = lg[j] - lse;
}

// ---------------------------------------------------------------------------
// Launch
// ---------------------------------------------------------------------------
extern "C" void kernel_launch(void* const* d_in, const int* in_sizes, int n_in,
                              void* d_out, int out_size, void* d_ws, size_t ws_size,
                              hipStream_t stream) {
    const float* x   = (const float*)d_in[0];
    const int*   ei  = (const int*)d_in[1];
    const int*   bat = (const int*)d_in[2];
    const float* W1  = (const float*)d_in[3];
    const float* b1  = (const float*)d_in[4];
    const float* W2  = (const float*)d_in[5];
    const float* b2  = (const float*)d_in[6];
    const float* Wfc = (const float*)d_in[7];
    const float* bfc = (const float*)d_in[8];
    float* out = (float*)d_out;

    const int* src = ei;
    const int* dst = ei + N_EDGES;

    // workspace layout (bytes, all 16B-aligned)
    char* ws = (char*)d_ws;
    float* dinv   = (float*)(ws + 0);                        //   400,000 B
    float* bufA   = (float*)(ws + 400000);                   // 25,600,000 B  (h)
    float* bufB   = (float*)(ws + 26000000);                 // 25,600,000 B  (agg / relu out)
    float* pooled = (float*)(ws + 51600000);                 //    131,072 B
    float* cnt    = (float*)(ws + 51731072);                 //      2,048 B

    // --- degree / dinv ---
    hipMemsetAsync(dinv, 0, (size_t)N_NODES * sizeof(float), stream);
    deg_count_kernel<<<(N_EDGES + 255) / 256, 256, 0, stream>>>(dst, dinv, N_EDGES);
    dinv_kernel<<<(N_NODES + 255) / 256, 256, 0, stream>>>(dinv, N_NODES);

    // --- layer 1: h1 = x @ W1 ---
    gemm64_kernel<D_IN><<<(N_NODES + 63) / 64, 256, 0, stream>>>(x, W1, bufA, N_NODES);

    hipMemsetAsync(bufB, 0, (size_t)N_NODES * 64 * sizeof(float), stream);
    edge_agg_kernel<<<(N_EDGES * 16) / 256, 256, 0, stream>>>(src, dst, dinv, bufA, bufB, N_EDGES);
    selfloop_bias_relu_kernel<<<(N_NODES * 16 + 255) / 256, 256, 0, stream>>>(bufB, bufA, dinv, b1, N_NODES);
    // r1 = bufB

    // --- layer 2: h2 = r1 @ W2 ---
    gemm64_kernel<HIDDEN><<<(N_NODES + 63) / 64, 256, 0, stream>>>(bufB, W2, bufA, N_NODES);

    hipMemsetAsync(bufB, 0, (size_t)N_NODES * 64 * sizeof(float), stream);
    edge_agg_kernel<<<(N_EDGES * 16) / 256, 256, 0, stream>>>(src, dst, dinv, bufA, bufB, N_EDGES);
    selfloop_bias_relu_kernel<<<(N_NODES * 16 + 255) / 256, 256, 0, stream>>>(bufB, bufA, dinv, b2, N_NODES);
    // r2 = bufB

    // --- pooling ---
    hipMemsetAsync(pooled, 0, (size_t)(N_GRAPHS * 64 + N_GRAPHS) * sizeof(float), stream);
    {
        const int chunk = 256;
        int waves  = (N_NODES + chunk - 1) / chunk;
        int blocks = (waves + 3) / 4;   // 4 waves per 256-thread block
        pool_kernel<<<blocks, 256, 0, stream>>>(bufB, bat, pooled, cnt, N_NODES, chunk);
    }

    // --- head ---
    head_kernel<<<(N_GRAPHS + 255) / 256, 256, 0, stream>>>(pooled, cnt, Wfc, bfc, out);
}

// Round 2
// 586.368 us; speedup vs baseline: 5.0121x; 5.0121x over previous
//
#include <hip/hip_runtime.h>
#include <cstdint>
#include <cstddef>

#define N_NODES   100000
#define N_EDGES   1600000
#define D_IN      128
#define HIDDEN    64
#define N_GRAPHS  512
#define N_CLASSES 10

// ===========================================================================
// Degree / dinv
// ===========================================================================
__global__ void deg_count_int_kernel(const int* __restrict__ dst, int* __restrict__ degi,
                                     int n_edges) {
    int t = blockIdx.x * blockDim.x + threadIdx.x;
    if (t >= n_edges) return;
    atomicAdd(&degi[dst[t]], 1);
}

__global__ void dinv_from_int_kernel(const int* __restrict__ degi, float* __restrict__ dinv,
                                     int n_nodes) {
    int t = blockIdx.x * blockDim.x + threadIdx.x;
    if (t >= n_nodes) return;
    dinv[t] = rsqrtf((float)degi[t] + 1.0f);
}

// float-atomic degree (fallback path)
__global__ void deg_count_f_kernel(const int* __restrict__ dst, float* __restrict__ deg,
                                   int n_edges) {
    int t = blockIdx.x * blockDim.x + threadIdx.x;
    if (t >= n_edges) return;
    unsafeAtomicAdd(&deg[dst[t]], 1.0f);
}

__global__ void dinv_kernel(float* __restrict__ deg, int n_nodes) {
    int t = blockIdx.x * blockDim.x + threadIdx.x;
    if (t >= n_nodes) return;
    deg[t] = rsqrtf(deg[t] + 1.0f);
}

// ===========================================================================
// Prefix scan over degi -> offs (exclusive), 1024 elems/block, 3 passes
// ===========================================================================
__global__ __launch_bounds__(256)
void scan1_kernel(const int* __restrict__ degi, int* __restrict__ bsum, int n) {
    __shared__ int lds[256];
    int tid = threadIdx.x;
    int base = blockIdx.x * 1024 + tid * 4;
    int s = 0;
#pragma unroll
    for (int j = 0; j < 4; j++) { int i = base + j; if (i < n) s += degi[i]; }
    lds[tid] = s; __syncthreads();
    for (int off = 128; off > 0; off >>= 1) {
        if (tid < off) lds[tid] += lds[tid + off];
        __syncthreads();
    }
    if (tid == 0) bsum[blockIdx.x] = lds[0];
}

// single block: exclusive scan of bsum (nb <= 256); writes offs[n] = total
__global__ __launch_bounds__(256)
void scan2_kernel(int* __restrict__ bsum, int* __restrict__ offs, int nb, int n) {
    __shared__ int lds[256];
    int tid = threadIdx.x;
    int v = (tid < nb) ? bsum[tid] : 0;
    lds[tid] = v; __syncthreads();
    for (int off = 1; off < 256; off <<= 1) {
        int t = (tid >= off) ? lds[tid - off] : 0;
        __syncthreads();
        lds[tid] += t;
        __syncthreads();
    }
    if (tid < nb) bsum[tid] = lds[tid] - v;   // exclusive
    if (tid == 255) offs[n] = lds[255];       // total
}

__global__ __launch_bounds__(256)
void scan3_kernel(const int* __restrict__ degi, const int* __restrict__ bsum,
                  int* __restrict__ offs, int n) {
    __shared__ int lds[256];
    int tid = threadIdx.x;
    int base = blockIdx.x * 1024 + tid * 4;
    int v[4]; int s = 0;
#pragma unroll
    for (int j = 0; j < 4; j++) {
        int i = base + j;
        v[j] = (i < n) ? degi[i] : 0;
        s += v[j];
    }
    lds[tid] = s; __syncthreads();
    for (int off = 1; off < 256; off <<= 1) {
        int t = (tid >= off) ? lds[tid - off] : 0;
        __syncthreads();
        lds[tid] += t;
        __syncthreads();
    }
    int ex = lds[tid] - s + bsum[blockIdx.x];
#pragma unroll
    for (int j = 0; j < 4; j++) {
        int i = base + j;
        if (i < n) { offs[i] = ex; ex += v[j]; }
    }
}

__global__ void copy_int_kernel(const int* __restrict__ a, int* __restrict__ b, int n) {
    int t = blockIdx.x * blockDim.x + threadIdx.x;
    if (t < n) b[t] = a[t];
}

// bucket fill: srcs_sorted grouped by dst
__global__ void fill_kernel(const int* __restrict__ src, const int* __restrict__ dst,
                            int* __restrict__ cursor, int* __restrict__ srcs_sorted,
                            int n_edges) {
    int t = blockIdx.x * blockDim.x + threadIdx.x;
    if (t >= n_edges) return;
    int d = dst[t];
    int pos = atomicAdd(&cursor[d], 1);
    srcs_sorted[pos] = src[t];
}

// ===========================================================================
// GEMM: H[n_rows x 64] = X[n_rows x K] @ W[K x 64]
// ===========================================================================
template <int K>
__global__ __launch_bounds__(256)
void gemm64_kernel(const float* __restrict__ X, const float* __restrict__ W,
                   float* __restrict__ H, int n_rows) {
    __shared__ float Xs[64][K + 4];
    __shared__ float Ws[K][64];

    const int tid  = threadIdx.x;
    const int row0 = blockIdx.x * 64;

    constexpr int WN4 = K * 64 / 4;
    const float4* W4 = (const float4*)W;
    float4* Ws4 = (float4*)&Ws[0][0];
    for (int i = tid; i < WN4; i += 256) Ws4[i] = W4[i];

    constexpr int KQ = K / 4;
    for (int i = tid; i < 64 * KQ; i += 256) {
        int r  = i / KQ;
        int k4 = i % KQ;
        int row = row0 + r;
        float4 v = make_float4(0.f, 0.f, 0.f, 0.f);
        if (row < n_rows) v = ((const float4*)(X + (size_t)row * K))[k4];
        *(float4*)&Xs[r][k4 * 4] = v;
    }
    __syncthreads();

    const int cg = (tid & 15) * 4;
    const int rg = (tid >> 4) * 4;

    float4 acc0 = make_float4(0.f,0.f,0.f,0.f);
    float4 acc1 = make_float4(0.f,0.f,0.f,0.f);
    float4 acc2 = make_float4(0.f,0.f,0.f,0.f);
    float4 acc3 = make_float4(0.f,0.f,0.f,0.f);

#pragma unroll 8
    for (int k = 0; k < K; k++) {
        float4 w = *(const float4*)&Ws[k][cg];
        float x0 = Xs[rg + 0][k];
        float x1 = Xs[rg + 1][k];
        float x2 = Xs[rg + 2][k];
        float x3 = Xs[rg + 3][k];
        acc0.x += x0 * w.x; acc0.y += x0 * w.y; acc0.z += x0 * w.z; acc0.w += x0 * w.w;
        acc1.x += x1 * w.x; acc1.y += x1 * w.y; acc1.z += x1 * w.z; acc1.w += x1 * w.w;
        acc2.x += x2 * w.x; acc2.y += x2 * w.y; acc2.z += x2 * w.z; acc2.w += x2 * w.w;
        acc3.x += x3 * w.x; acc3.y += x3 * w.y; acc3.z += x3 * w.z; acc3.w += x3 * w.w;
    }

    float4 accs[4] = {acc0, acc1, acc2, acc3};
#pragma unroll
    for (int i = 0; i < 4; i++) {
        int row = row0 + rg + i;
        if (row < n_rows) *(float4*)(H + (size_t)row * 64 + cg) = accs[i];
    }
}

// ===========================================================================
// CSR gather aggregation, fused self-loop + bias + relu.
// 16 lanes per node, 4 channels each.
// out[n] = relu( sum_{s in N(n)} h[s]*dinv[s]*dinv[n]  +  h[n]*dinv[n]^2 + b )
// ===========================================================================
__global__ __launch_bounds__(256)
void gather_agg_kernel(const int* __restrict__ offs, const int* __restrict__ srcs_sorted,
                       const float* __restrict__ dinv, const float* __restrict__ h,
                       const float* __restrict__ b, float* __restrict__ out, int n_nodes) {
    int t = blockIdx.x * blockDim.x + threadIdx.x;
    int node = t >> 4;
    if (node >= n_nodes) return;
    int cg = (t & 15) * 4;

    float dn = dinv[node];
    float c2 = dn * dn;
    float4 hv = *(const float4*)(h + (size_t)node * 64 + cg);
    float4 acc;
    acc.x = hv.x * c2; acc.y = hv.y * c2; acc.z = hv.z * c2; acc.w = hv.w * c2;

    int i0 = offs[node];
    int i1 = offs[node + 1];
    for (int i = i0; i < i1; i++) {
        int s = srcs_sorted[i];
        float c = dinv[s] * dn;
        float4 v = *(const float4*)(h + (size_t)s * 64 + cg);
        acc.x += v.x * c; acc.y += v.y * c; acc.z += v.z * c; acc.w += v.w * c;
    }

    float4 bv = *(const float4*)(b + cg);
    float4 r;
    r.x = fmaxf(acc.x + bv.x, 0.f);
    r.y = fmaxf(acc.y + bv.y, 0.f);
    r.z = fmaxf(acc.z + bv.z, 0.f);
    r.w = fmaxf(acc.w + bv.w, 0.f);
    *(float4*)(out + (size_t)node * 64 + cg) = r;
}

// ===========================================================================
// Fallback path kernels (scatter atomics) — used only if ws too small
// ===========================================================================
__global__ __launch_bounds__(256)
void edge_agg_kernel(const int* __restrict__ src, const int* __restrict__ dst,
                     const float* __restrict__ dinv, const float* __restrict__ h,
                     float* __restrict__ agg, int n_edges) {
    int t = blockIdx.x * blockDim.x + threadIdx.x;
    int e = t >> 4;
    if (e >= n_edges) return;
    int cg = (t & 15) * 4;
    int s = src[e];
    int d = dst[e];
    float coef = dinv[s] * dinv[d];
    float4 v = *(const float4*)(h + (size_t)s * 64 + cg);
    float* out = agg + (size_t)d * 64 + cg;
    unsafeAtomicAdd(out + 0, v.x * coef);
    unsafeAtomicAdd(out + 1, v.y * coef);
    unsafeAtomicAdd(out + 2, v.z * coef);
    unsafeAtomicAdd(out + 3, v.w * coef);
}

__global__ __launch_bounds__(256)
void selfloop_bias_relu_kernel(float* __restrict__ agg, const float* __restrict__ h,
                               const float* __restrict__ dinv, const float* __restrict__ b,
                               int n_nodes) {
    int t = blockIdx.x * blockDim.x + threadIdx.x;
    int node = t >> 4;
    if (node >= n_nodes) return;
    int cg = (t & 15) * 4;
    float di = dinv[node];
    float c2 = di * di;
    float4 a  = *(const float4*)(agg + (size_t)node * 64 + cg);
    float4 hv = *(const float4*)(h   + (size_t)node * 64 + cg);
    float4 bv = *(const float4*)(b + cg);
    float4 r;
    r.x = fmaxf(a.x + hv.x * c2 + bv.x, 0.f);
    r.y = fmaxf(a.y + hv.y * c2 + bv.y, 0.f);
    r.z = fmaxf(a.z + hv.z * c2 + bv.z, 0.f);
    r.w = fmaxf(a.w + hv.w * c2 + bv.w, 0.f);
    *(float4*)(agg + (size_t)node * 64 + cg) = r;
}

// ===========================================================================
// Pooling (batch sorted) + head
// ===========================================================================
__global__ __launch_bounds__(256)
void pool_kernel(const float* __restrict__ h, const int* __restrict__ batch,
                 float* __restrict__ pooled, float* __restrict__ cnt,
                 int n_nodes, int chunk) {
    int wave = (blockIdx.x * blockDim.x + threadIdx.x) >> 6;
    int lane = threadIdx.x & 63;
    int start = wave * chunk;
    if (start >= n_nodes) return;
    int end = min(start + chunk, n_nodes);

    int cur = batch[start];
    float acc = 0.f;
    float c = 0.f;
    for (int i = start; i < end; i++) {
        int g = batch[i];
        if (g != cur) {
            unsafeAtomicAdd(&pooled[(size_t)cur * 64 + lane], acc);
            if (lane == 0) unsafeAtomicAdd(&cnt[cur], c);
            acc = 0.f; c = 0.f; cur = g;
        }
        acc += h[(size_t)i * 64 + lane];
        c += 1.f;
    }
    unsafeAtomicAdd(&pooled[(size_t)cur * 64 + lane], acc);
    if (lane == 0) unsafeAtomicAdd(&cnt[cur], c);
}

__global__ __launch_bounds__(256)
void head_kernel(const float* __restrict__ pooled, const float* __restrict__ cnt,
                 const float* __restrict__ Wfc, const float* __restrict__ bfc,
                 float* __restrict__ out) {
    __shared__ float Ws[HIDDEN * N_CLASSES];
    __shared__ float bs[N_CLASSES];
    int tid = threadIdx.x;
    for (int i = tid; i < HIDDEN * N_CLASSES; i += 256) Ws[i] = Wfc[i];
    if (tid < N_CLASSES) bs[tid] = bfc[tid];
    __syncthreads();

    int g = blockIdx.x * 256 + tid;
    if (g >= N_GRAPHS) return;

    float inv = 1.f / fmaxf(cnt[g], 1.f);
    float p[HIDDEN];
#pragma unroll
    for (int k = 0; k < HIDDEN; k++) p[k] = pooled[(size_t)g * 64 + k] * inv;

    float lg[N_CLASSES];
    float m = -1e30f;
#pragma unroll
    for (int j = 0; j < N_CLASSES; j++) {
        float a = bs[j];
#pragma unroll
        for (int k = 0; k < HIDDEN; k++) a += p[k] * Ws[k * N_CLASSES + j];
        lg[j] = a;
        m = fmaxf(m, a);
    }
    float s = 0.f;
#pragma unroll
    for (int j = 0; j < N_CLASSES; j++) s += __expf(lg[j] - m);
    float lse = m + __logf(s);
#pragma unroll
    for (int j = 0; j < N_CLASSES; j++) out[(size_t)g * N_CLASSES + j] = lg[j] - lse;
}

// ===========================================================================
// Launch
// ===========================================================================
extern "C" void kernel_launch(void* const* d_in, const int* in_sizes, int n_in,
                              void* d_out, int out_size, void* d_ws, size_t ws_size,
                              hipStream_t stream) {
    const float* x   = (const float*)d_in[0];
    const int*   ei  = (const int*)d_in[1];
    const int*   bat = (const int*)d_in[2];
    const float* W1  = (const float*)d_in[3];
    const float* b1  = (const float*)d_in[4];
    const float* W2  = (const float*)d_in[5];
    const float* b2  = (const float*)d_in[6];
    const float* Wfc = (const float*)d_in[7];
    const float* bfc = (const float*)d_in[8];
    float* out = (float*)d_out;

    const int* src = ei;
    const int* dst = ei + N_EDGES;

    char* ws = (char*)d_ws;

    // ---- CSR-gather layout ----
    const size_t OFF_BUFA = 0;            // 25,600,000
    const size_t OFF_BUFB = 25600000;     // 25,600,000
    const size_t OFF_DINV = 51200000;     //    400,000
    const size_t OFF_OFFS = 51600000;     //    400,016 (N+1 ints, padded)
    const size_t OFF_DEGI = 52000016;     //    400,000 (reused as cursor)
    const size_t OFF_BSUM = 52400016;     //      2,048
    const size_t OFF_POOL = 52402064;     //    131,072
    const size_t OFF_CNT  = 52533136;     //      2,048
    const size_t OFF_SRCS = 52535184;     //  6,400,000
    const size_t NEEDED   = 58935184;

    const int SCAN_BLOCKS = (N_NODES + 1023) / 1024;  // 98

    if (ws_size >= NEEDED) {
        float* bufA   = (float*)(ws + OFF_BUFA);
        float* bufB   = (float*)(ws + OFF_BUFB);
        float* dinv   = (float*)(ws + OFF_DINV);
        int*   offs   = (int*)  (ws + OFF_OFFS);
        int*   degi   = (int*)  (ws + OFF_DEGI);   // also cursor
        int*   bsum   = (int*)  (ws + OFF_BSUM);
        float* pooled = (float*)(ws + OFF_POOL);
        float* cnt    = (float*)(ws + OFF_CNT);
        int*   srcs   = (int*)  (ws + OFF_SRCS);

        // --- build CSR (once, reused by both layers) ---
        hipMemsetAsync(degi, 0, (size_t)N_NODES * sizeof(int), stream);
        deg_count_int_kernel<<<(N_EDGES + 255) / 256, 256, 0, stream>>>(dst, degi, N_EDGES);
        dinv_from_int_kernel<<<(N_NODES + 255) / 256, 256, 0, stream>>>(degi, dinv, N_NODES);
        scan1_kernel<<<SCAN_BLOCKS, 256, 0, stream>>>(degi, bsum, N_NODES);
        scan2_kernel<<<1, 256, 0, stream>>>(bsum, offs, SCAN_BLOCKS, N_NODES);
        scan3_kernel<<<SCAN_BLOCKS, 256, 0, stream>>>(degi, bsum, offs, N_NODES);
        copy_int_kernel<<<(N_NODES + 255) / 256, 256, 0, stream>>>(offs, degi, N_NODES); // cursor
        fill_kernel<<<(N_EDGES + 255) / 256, 256, 0, stream>>>(src, dst, degi, srcs, N_EDGES);

        // --- layer 1 ---
        gemm64_kernel<D_IN><<<(N_NODES + 63) / 64, 256, 0, stream>>>(x, W1, bufA, N_NODES);
        gather_agg_kernel<<<(N_NODES * 16 + 255) / 256, 256, 0, stream>>>(
            offs, srcs, dinv, bufA, b1, bufB, N_NODES);

        // --- layer 2 ---
        gemm64_kernel<HIDDEN><<<(N_NODES + 63) / 64, 256, 0, stream>>>(bufB, W2, bufA, N_NODES);
        gather_agg_kernel<<<(N_NODES * 16 + 255) / 256, 256, 0, stream>>>(
            offs, srcs, dinv, bufA, b2, bufB, N_NODES);

        // --- pooling + head ---
        hipMemsetAsync(pooled, 0, (size_t)N_GRAPHS * 64 * sizeof(float), stream);
        hipMemsetAsync(cnt, 0, (size_t)N_GRAPHS * sizeof(float), stream);
        {
            const int chunk = 256;
            int waves  = (N_NODES + chunk - 1) / chunk;
            int blocks = (waves + 3) / 4;
            pool_kernel<<<blocks, 256, 0, stream>>>(bufB, bat, pooled, cnt, N_NODES, chunk);
        }
        head_kernel<<<(N_GRAPHS + 255) / 256, 256, 0, stream>>>(pooled, cnt, Wfc, bfc, out);
    } else {
        // ---- fallback: round-1 scatter-atomic path (ws >= 51,733,120 known good) ----
        float* dinv   = (float*)(ws + 0);
        float* bufA   = (float*)(ws + 400000);
        float* bufB   = (float*)(ws + 26000000);
        float* pooled = (float*)(ws + 51600000);
        float* cnt    = (float*)(ws + 51731072);

        hipMemsetAsync(dinv, 0, (size_t)N_NODES * sizeof(float), stream);
        deg_count_f_kernel<<<(N_EDGES + 255) / 256, 256, 0, stream>>>(dst, dinv, N_EDGES);
        dinv_kernel<<<(N_NODES + 255) / 256, 256, 0, stream>>>(dinv, N_NODES);

        gemm64_kernel<D_IN><<<(N_NODES + 63) / 64, 256, 0, stream>>>(x, W1, bufA, N_NODES);
        hipMemsetAsync(bufB, 0, (size_t)N_NODES * 64 * sizeof(float), stream);
        edge_agg_kernel<<<(N_EDGES * 16) / 256, 256, 0, stream>>>(src, dst, dinv, bufA, bufB, N_EDGES);
        selfloop_bias_relu_kernel<<<(N_NODES * 16 + 255) / 256, 256, 0, stream>>>(bufB, bufA, dinv, b1, N_NODES);

        gemm64_kernel<HIDDEN><<<(N_NODES + 63) / 64, 256, 0, stream>>>(bufB, W2, bufA, N_NODES);
        hipMemsetAsync(bufB, 0, (size_t)N_NODES * 64 * sizeof(float), stream);
        edge_agg_kernel<<<(N_EDGES * 16) / 256, 256, 0, stream>>>(src, dst, dinv, bufA, bufB, N_EDGES);
        selfloop_bias_relu_kernel<<<(N_NODES * 16 + 255) / 256, 256, 0, stream>>>(bufB, bufA, dinv, b2, N_NODES);

        hipMemsetAsync(pooled, 0, (size_t)(N_GRAPHS * 64 + N_GRAPHS) * sizeof(float), stream);
        {
            const int chunk = 256;
            int waves  = (N_NODES + chunk - 1) / chunk;
            int blocks = (waves + 3) / 4;
            pool_kernel<<<blocks, 256, 0, stream>>>(bufB, bat, pooled, cnt, N_NODES, chunk);
        }
        head_kernel<<<(N_GRAPHS + 255) / 256, 256, 0, stream>>>(pooled, cnt, Wfc, bfc, out);
    }
}